// Round 2
// baseline (330.631 us; speedup 1.0000x reference)
//
#include <hip/hip_runtime.h>
#include <math.h>

#define BB 128
#define TT 2048
#define OO 128
#define EE 512
#define LL 34
#define XDIM 640       // O+E
#define SUBCH 64       // flash partials per batch row
#define SUB_LEN 32     // rows per wave

__device__ __forceinline__ float sigmoidf_(float x) { return 1.0f / (1.0f + __expf(-x)); }

// ---------------- K1: LSTM cell, fused GEMM + activation.
// grid (8 o-tiles of 16, 32 batch-quads) = 256 blocks x 256 threads.
__global__ __launch_bounds__(256) void lstm_kernel(
    const float* __restrict__ y1, const float* __restrict__ c1,
    const float* __restrict__ sh1, const float* __restrict__ sc1,
    const float* __restrict__ Wih, const float* __restrict__ bih,
    const float* __restrict__ Whh, const float* __restrict__ bhh,
    float* __restrict__ out_sh, float* __restrict__ out_sc)
{
    __shared__ float xs[4][768];          // per batch row: [y1(512)|c1(128)|sh1(128)]
    __shared__ float gbuf[4][4][16];      // [gate][bi][o_local]
    const int tid = threadIdx.x;
    const int otile = blockIdx.x;
    const int qb = blockIdx.y * 4;

    for (int idx = tid; idx < 4 * 768; idx += 256) {
        int bi = idx / 768, k = idx - bi * 768;
        int b = qb + bi;
        float v;
        if (k < 512)      v = y1[b * EE + k];
        else if (k < 640) v = c1[b * OO + (k - 512)];
        else              v = sh1[b * OO + (k - 640)];
        xs[bi][k] = v;
    }
    __syncthreads();

    const int g = tid >> 6, l = tid & 63;   // wave g = gate g
    #pragma unroll 2
    for (int i = 0; i < 16; ++i) {
        const int row = g * 128 + otile * 16 + i;
        const float* wr = Wih + (size_t)row * XDIM;
        float a0 = 0.f, a1 = 0.f, a2 = 0.f, a3 = 0.f;
        #pragma unroll
        for (int j = 0; j < 10; ++j) {
            float wv = wr[l + 64 * j];
            a0 += wv * xs[0][l + 64 * j];
            a1 += wv * xs[1][l + 64 * j];
            a2 += wv * xs[2][l + 64 * j];
            a3 += wv * xs[3][l + 64 * j];
        }
        const float* wh = Whh + (size_t)row * OO;
        #pragma unroll
        for (int j = 0; j < 2; ++j) {
            float wv = wh[l + 64 * j];
            a0 += wv * xs[0][640 + l + 64 * j];
            a1 += wv * xs[1][640 + l + 64 * j];
            a2 += wv * xs[2][640 + l + 64 * j];
            a3 += wv * xs[3][640 + l + 64 * j];
        }
        #pragma unroll
        for (int off = 32; off >= 1; off >>= 1) {
            a0 += __shfl_xor(a0, off);
            a1 += __shfl_xor(a1, off);
            a2 += __shfl_xor(a2, off);
            a3 += __shfl_xor(a3, off);
        }
        if (l == 0) {
            float bb = bih[row] + bhh[row];
            gbuf[g][0][i] = a0 + bb;
            gbuf[g][1][i] = a1 + bb;
            gbuf[g][2][i] = a2 + bb;
            gbuf[g][3][i] = a3 + bb;
        }
    }
    __syncthreads();

    if (tid < 64) {
        const int bi = tid >> 4, ol = tid & 15;
        const int b = qb + bi, o = otile * 16 + ol;
        float gi = gbuf[0][bi][ol], gf = gbuf[1][bi][ol];
        float gg = gbuf[2][bi][ol], go = gbuf[3][bi][ol];
        float sc = sigmoidf_(gf) * sc1[b * OO + o] + sigmoidf_(gi) * tanhf(gg);
        float sh = sigmoidf_(go) * tanhf(sc);
        out_sc[b * OO + o] = sc;
        out_sh[b * OO + o] = sh;
    }
}

// ---------------- K2: barrier-free flash attention partials.
// One 64-lane WAVE per 32-row sub-chunk; 4 independent waves per block, zero
// __syncthreads. hk loads are UNCONDITIONAL (mask applied arithmetically, never
// as a load guard -> no mask->load dependent chain). Per-wave (m,S) via
// shfl_xor only. hv phase is gated on the wave-uniform S==0 (dead sub-chunk)
// and consumed as float4 (16B/lane). Unnormalized partials; renorm in K3.
__global__ __launch_bounds__(256) void attn_kernel(
    const float* __restrict__ hk, const float* __restrict__ hv,
    const float* __restrict__ mask, const float* __restrict__ sc,
    float* __restrict__ ws_c, float2* __restrict__ pbuf)
{
    const int b = blockIdx.y;
    const int tid = threadIdx.x;
    const int wave = tid >> 6, lane = tid & 63;
    const int subchunk = blockIdx.x * 4 + wave;     // 0..63
    const int sg = (lane >> 4) & 3, l = lane & 15;  // 4 subgroups x 16 lanes
    const int r0 = subchunk * SUB_LEN;

    // ---- scores: each subgroup handles 8 rows; 32B/lane/row from hk.
    const float4 scA = *(const float4*)(sc + b * OO + l * 8);
    const float4 scB = *(const float4*)(sc + b * OO + l * 8 + 4);
    const float* krow = hk + ((size_t)b * TT + r0 + sg * 8) * OO;
    const float* mrow = mask + (size_t)b * TT + r0 + sg * 8;

    float s[8];
    bool val[8];
    #pragma unroll
    for (int i = 0; i < 8; ++i) {
        val[i] = (mrow[i] != 0.f);          // independent load, not a guard
        float4 a  = *(const float4*)(krow + (size_t)i * OO + l * 8);
        float4 c2 = *(const float4*)(krow + (size_t)i * OO + l * 8 + 4);
        s[i] = a.x * scA.x + a.y * scA.y + a.z * scA.z + a.w * scA.w
             + c2.x * scB.x + c2.y * scB.y + c2.z * scB.z + c2.w * scB.w;
    }
    #pragma unroll
    for (int i = 0; i < 8; ++i) {
        s[i] += __shfl_xor(s[i], 8);
        s[i] += __shfl_xor(s[i], 4);
        s[i] += __shfl_xor(s[i], 2);
        s[i] += __shfl_xor(s[i], 1);
    }
    float m = -INFINITY;
    #pragma unroll
    for (int i = 0; i < 8; ++i) if (val[i]) m = fmaxf(m, s[i]);
    m = fmaxf(m, __shfl_xor(m, 16));
    m = fmaxf(m, __shfl_xor(m, 32));        // wave-wide max (uniform)

    float e[8];
    float ps = 0.f;
    #pragma unroll
    for (int i = 0; i < 8; ++i) {
        e[i] = val[i] ? __expf(s[i] - m) : 0.f;
        ps += e[i];
    }
    ps += __shfl_xor(ps, 16);
    ps += __shfl_xor(ps, 32);               // wave-wide sum (uniform)
    if (lane == 0)
        pbuf[(size_t)b * SUBCH + subchunk] = make_float2(m, ps);

    // ---- weighted sum over hv: lane covers 4 cols, 2 row-interleave groups.
    const int c4 = (lane & 31) * 4, rp = lane >> 5;
    float4 acc = make_float4(0.f, 0.f, 0.f, 0.f);
    if (ps > 0.f) {                          // wave-uniform: skip dead sub-chunks
        const float* vbase = hv + ((size_t)b * TT + r0) * OO + c4;
        #pragma unroll
        for (int sgi = 0; sgi < 4; ++sgi) {
            float wv[8];
            #pragma unroll
            for (int i = 0; i < 8; ++i) wv[i] = __shfl(e[i], sgi * 16);
            #pragma unroll
            for (int j = 0; j < 4; ++j) {
                const int row = sgi * 8 + j * 2 + rp;
                float4 v = *(const float4*)(vbase + (size_t)row * OO);
                float w = (rp == 0) ? wv[2 * j] : wv[2 * j + 1];  // static idx + cndmask
                acc.x += w * v.x;
                acc.y += w * v.y;
                acc.z += w * v.z;
                acc.w += w * v.w;
            }
        }
    }
    acc.x += __shfl_xor(acc.x, 32);
    acc.y += __shfl_xor(acc.y, 32);
    acc.z += __shfl_xor(acc.z, 32);
    acc.w += __shfl_xor(acc.w, 32);
    if (rp == 0)
        *(float4*)(ws_c + ((size_t)b * SUBCH + subchunk) * OO + c4) = acc;
}

// ---------------- K3: combine 64 flash partials (global renorm) -> c, MLP head.
__global__ __launch_bounds__(256) void final_kernel(
    const float* __restrict__ ws_c, const float2* __restrict__ pbuf,
    const float* __restrict__ sh_in,
    const float* __restrict__ W1, const float* __restrict__ b1,
    const float* __restrict__ W2, const float* __restrict__ b2,
    const float* __restrict__ W3, const float* __restrict__ b3,
    float* __restrict__ out_p, float* __restrict__ out_c)
{
    const int b = blockIdx.x, tid = threadIdx.x;
    __shared__ float marr[SUBCH], Sarr[SUBCH], fac[SUBCH];
    __shared__ float cbuf[128], shbuf[128], h1[LL], zz[LL], red2[2];

    if (tid < SUBCH) {
        float2 p = pbuf[(size_t)b * SUBCH + tid];
        marr[tid] = p.x;
        Sarr[tid] = p.y;
    }
    __syncthreads();
    if (tid < SUBCH) {
        float M = marr[0];
        #pragma unroll
        for (int i = 1; i < SUBCH; ++i) M = fmaxf(M, marr[i]);
        float S = 0.f;
        #pragma unroll
        for (int i = 0; i < SUBCH; ++i) S += Sarr[i] * __expf(marr[i] - M);
        fac[tid] = __expf(marr[tid] - M) / S;   // 0 for dead sub-chunk (marr=-inf)
    }
    __syncthreads();

    if (tid < 128) {
        float s = 0.f;
        const float* base = ws_c + (size_t)b * SUBCH * OO + tid;
        #pragma unroll 8
        for (int i = 0; i < SUBCH; ++i) s += fac[i] * base[i * OO];
        cbuf[tid] = s;
        out_c[b * OO + tid] = s;
        shbuf[tid] = sh_in[b * OO + tid];
    }
    __syncthreads();

    const int o = tid >> 2, l2 = tid & 3;
    if (o < LL) {
        float a = 0.f;
        const float* w1r = W1 + o * OO;
        const float* w2r = W2 + o * OO;
        #pragma unroll 8
        for (int j = 0; j < 32; ++j) {
            int k = l2 + 4 * j;
            a += w1r[k] * shbuf[k] + w2r[k] * cbuf[k];
        }
        a += __shfl_xor(a, 1);
        a += __shfl_xor(a, 2);
        if (l2 == 0) h1[o] = fmaxf(a + b1[o] + b2[o], 0.f);
    }
    __syncthreads();

    if (o < LL) {
        float z = 0.f;
        const float* w3r = W3 + o * LL;
        for (int j = 0; j < 9; ++j) {
            int k = l2 + 4 * j;
            if (k < LL) z += w3r[k] * h1[k];
        }
        z += __shfl_xor(z, 1);
        z += __shfl_xor(z, 2);
        if (l2 == 0) zz[o] = z + b3[o];
    }
    __syncthreads();
    if (tid == 0) {
        float mm = zz[0];
        for (int i = 1; i < LL; i++) mm = fmaxf(mm, zz[i]);
        float ss = 0.f;
        for (int i = 0; i < LL; i++) ss += __expf(zz[i] - mm);
        red2[0] = mm; red2[1] = ss;
    }
    __syncthreads();
    if (tid < LL) out_p[b * LL + tid] = __expf(zz[tid] - red2[0]) / red2[1];
}

extern "C" void kernel_launch(void* const* d_in, const int* in_sizes, int n_in,
                              void* d_out, int out_size, void* d_ws, size_t ws_size,
                              hipStream_t stream) {
    (void)in_sizes; (void)n_in; (void)out_size; (void)ws_size;
    const float* hk   = (const float*)d_in[0];
    const float* hv   = (const float*)d_in[1];
    const float* y1   = (const float*)d_in[2];
    const float* c1   = (const float*)d_in[3];
    const float* sh1  = (const float*)d_in[4];
    const float* sc1  = (const float*)d_in[5];
    const float* mask = (const float*)d_in[6];
    const float* Wih  = (const float*)d_in[7];
    const float* bih  = (const float*)d_in[8];
    const float* Whh  = (const float*)d_in[9];
    const float* bhh  = (const float*)d_in[10];
    const float* W1   = (const float*)d_in[11];
    const float* b1   = (const float*)d_in[12];
    const float* W2   = (const float*)d_in[13];
    const float* b2   = (const float*)d_in[14];
    const float* W3   = (const float*)d_in[15];
    const float* b3   = (const float*)d_in[16];

    float* out    = (float*)d_out;        // [B, L]
    float* out_c  = out + BB * LL;        // [B, O]
    float* out_sh = out_c + BB * OO;      // [B, O]
    float* out_sc = out_sh + BB * OO;     // [B, O]

    float*  ws_c = (float*)d_ws;                                // [B, SUBCH, O] (4 MB)
    float2* pbuf = (float2*)(ws_c + (size_t)BB * SUBCH * OO);   // [B, SUBCH] (m,S) 64 KB

    lstm_kernel<<<dim3(8, 32), 256, 0, stream>>>(y1, c1, sh1, sc1, Wih, bih, Whh, bhh,
                                                 out_sh, out_sc);
    attn_kernel<<<dim3(SUBCH / 4, BB), 256, 0, stream>>>(hk, hv, mask, out_sc, ws_c, pbuf);
    final_kernel<<<BB, 256, 0, stream>>>(ws_c, pbuf, out_sh, W1, b1, W2, b2, W3, b3,
                                         out, out_c);
}